// Round 4
// baseline (584.754 us; speedup 1.0000x reference)
//
#include <hip/hip_runtime.h>

// Problem constants (fixed by the reference):
//   x        [B=4096, D=16384] fp32
//   hashProj [D=16384, E=1024] fp32, exactly one nonzero (+-1) per row
//   out      [B=4096, E=1024]  fp32 = x @ hashProj
#define DIM_D 16384
#define DIM_E 1024
#define DIM_B 4096
#define QT_N  4      // feature-dimension quarters
#define QT_D  4096   // features per quarter (4096 * float4 = 64 KiB LDS)
#define CAP   32     // ELL slots per (bucket, quarter); counts ~Poisson(4)

// ---------------------------------------------------------------------------
// Kernel 1: extract (idx, sgn) per feature row from the dense hash projection
// (one wave per row, coalesced float4 scan; exactly one lane sees +-1).
// Also prefills the ELL tables with -1 and zeroes cursors/meta so no memset
// dispatch is needed.
// ---------------------------------------------------------------------------
__global__ __launch_bounds__(256) void hash_extract_kernel(
    const float* __restrict__ hashProj,
    int* __restrict__ idx, float* __restrict__ sgn,
    int* __restrict__ cursor /* [QT_N*1024] */, int* __restrict__ meta /* [16] */,
    int* __restrict__ ell /* [QT_N*CAP*1024] */) {
  const int gid = blockIdx.x * 256 + threadIdx.x;

  if (gid < QT_N * CAP * (DIM_E / 4)) {          // 32768 int4 = 512 KiB
    ((int4*)ell)[gid] = make_int4(-1, -1, -1, -1);
  }
  if (gid < QT_N * DIM_E) cursor[gid] = 0;
  if (gid < 16) meta[gid] = 0;

  const int wave = threadIdx.x >> 6;
  const int lane = threadIdx.x & 63;
  const int row = blockIdx.x * 4 + wave;         // 4096 blocks x 4 waves
  const float4* rp = (const float4*)(hashProj + (size_t)row * DIM_E);
  int found_e = -1;
  float found_s = 0.f;
#pragma unroll
  for (int k = 0; k < 4; ++k) {
    const int p = lane + 64 * k;
    float4 v = rp[p];
    const int base = p * 4;
    if (v.x != 0.f) { found_e = base + 0; found_s = v.x; }
    if (v.y != 0.f) { found_e = base + 1; found_s = v.y; }
    if (v.z != 0.f) { found_e = base + 2; found_s = v.z; }
    if (v.w != 0.f) { found_e = base + 3; found_s = v.w; }
  }
  if (found_e >= 0) {
    idx[row] = found_e;
    sgn[row] = found_s;
  }
}

// ---------------------------------------------------------------------------
// Kernel 2: fill per-quarter transposed ELL. Slot s of bucket e in quarter qt
// lives at ell[(qt*CAP + s)*1024 + e] (e lane-consecutive -> coalesced slot
// loads in the gather). Entry payload = local feature index (j & 4095);
// sign is NOT stored (applied at staging time via sgn[]). meta[qt] = max slot.
// ---------------------------------------------------------------------------
__global__ __launch_bounds__(256) void hash_fill_kernel(
    const int* __restrict__ idx,
    int* __restrict__ cursor, int* __restrict__ meta,
    int* __restrict__ ell) {
  const int j = blockIdx.x * 256 + threadIdx.x;
  const int e = idx[j];
  const int qt = j >> 12;
  const int s = atomicAdd(&cursor[qt * DIM_E + e], 1);
  if (s < CAP) ell[(qt * CAP + s) * DIM_E + e] = j & (QT_D - 1);
  atomicMax(&meta[qt], s);
}

// ---------------------------------------------------------------------------
// Kernel 3: gather, 4 batch rows per block. For each feature-quarter:
// stage xs4[local_j] = sign_j * (x[b0..b0+3][j]) (transposed float4 pack,
// XOR-swizzled so the b128 staging writes spread across all bank groups),
// then thread e walks its bucket's slots with ONE ds_read_b128 per entry
// serving all 4 rows. Uniform per-quarter trip count (no divergence); pad
// entries (-1) decode to a masked broadcast read. No atomics in the hot path.
// ---------------------------------------------------------------------------
__global__ __launch_bounds__(1024) void hash_gather_kernel(
    const float* __restrict__ x, const float* __restrict__ sgn,
    const int* __restrict__ meta, const int* __restrict__ ell,
    float* __restrict__ out) {
  __shared__ float4 xs4[QT_D];                   // 64 KiB -> 2 blocks/CU
  const int t = threadIdx.x;
  const int b0 = blockIdx.x * 4;
  const int e = t;
  const float* x0 = x + (size_t)(b0 + 0) * DIM_D;
  const float* x1 = x + (size_t)(b0 + 1) * DIM_D;
  const float* x2 = x + (size_t)(b0 + 2) * DIM_D;
  const float* x3 = x + (size_t)(b0 + 3) * DIM_D;

  float s0 = 0.f, s1 = 0.f, s2 = 0.f, s3 = 0.f;

  for (int qt = 0; qt < QT_N; ++qt) {
    __syncthreads();                             // xs4 reuse fence
#pragma unroll
    for (int i = 0; i < QT_D / 1024; ++i) {      // 4 local_j per thread
      const int lj = t + i * 1024;               // stride-1024: swizzled write
      const int j = qt * QT_D + lj;              //   addrs hit all bank groups
      const float sg = sgn[j];
      const float v0 = x0[j], v1 = x1[j], v2 = x2[j], v3 = x3[j];
      const int sj = lj ^ ((lj >> 3) & 7);       // XOR swizzle
      xs4[sj] = make_float4(sg * v0, sg * v1, sg * v2, sg * v3);
    }
    __syncthreads();

    int trip = meta[qt] + 1;                     // uniform slot count (~15)
    if (trip > CAP) trip = CAP;
    const int* ep = ell + (qt * CAP) * DIM_E + e;
    int q = ep[0];                               // prefetch slot 0
    for (int s = 1; s < trip; ++s) {
      const int qn = ep[s * DIM_E];              // prefetch next (L2-hot)
      const int jm = q & (QT_D - 1);
      const int sj = jm ^ ((jm >> 3) & 7);
      const float4 v = xs4[sj];                  // one b128 serves 4 rows
      const int m = ~(q >> 31);                  // pad (-1) -> zero mask
      s0 += __int_as_float(__float_as_int(v.x) & m);
      s1 += __int_as_float(__float_as_int(v.y) & m);
      s2 += __int_as_float(__float_as_int(v.z) & m);
      s3 += __int_as_float(__float_as_int(v.w) & m);
      q = qn;
    }
    {                                            // last slot
      const int jm = q & (QT_D - 1);
      const int sj = jm ^ ((jm >> 3) & 7);
      const float4 v = xs4[sj];
      const int m = ~(q >> 31);
      s0 += __int_as_float(__float_as_int(v.x) & m);
      s1 += __int_as_float(__float_as_int(v.y) & m);
      s2 += __int_as_float(__float_as_int(v.z) & m);
      s3 += __int_as_float(__float_as_int(v.w) & m);
    }
  }

  out[(size_t)(b0 + 0) * DIM_E + e] = s0;
  out[(size_t)(b0 + 1) * DIM_E + e] = s1;
  out[(size_t)(b0 + 2) * DIM_E + e] = s2;
  out[(size_t)(b0 + 3) * DIM_E + e] = s3;
}

extern "C" void kernel_launch(void* const* d_in, const int* in_sizes, int n_in,
                              void* d_out, int out_size, void* d_ws, size_t ws_size,
                              hipStream_t stream) {
  const float* x = (const float*)d_in[0];
  const float* hashProj = (const float*)d_in[1];
  float* out = (float*)d_out;

  // Workspace layout (16B-aligned sections):
  //   idx    [16384] int          ( 64 KiB)
  //   sgn    [16384] float        ( 64 KiB)
  //   cursor [QT_N*1024] int      ( 16 KiB)
  //   meta   [16] int
  //   ell    [QT_N*CAP*1024] int  (512 KiB)
  char* ws = (char*)d_ws;
  int*   idx    = (int*)ws;                ws += DIM_D * sizeof(int);
  float* sgn    = (float*)ws;              ws += DIM_D * sizeof(float);
  int*   cursor = (int*)ws;                ws += QT_N * DIM_E * sizeof(int);
  int*   meta   = (int*)ws;                ws += 16 * sizeof(int);
  int*   ell    = (int*)ws;

  hash_extract_kernel<<<DIM_D / 4, 256, 0, stream>>>(hashProj, idx, sgn, cursor, meta, ell);
  hash_fill_kernel<<<DIM_D / 256, 256, 0, stream>>>(idx, cursor, meta, ell);
  hash_gather_kernel<<<DIM_B / 4, 1024, 0, stream>>>(x, sgn, meta, ell, out);
}